// Round 13
// baseline (135.930 us; speedup 1.0000x reference)
//
#include <hip/hip_runtime.h>

typedef unsigned short u16;
typedef unsigned int   u32;
typedef unsigned long long u64;
typedef long long i64;

constexpr int DOF    = 300000;
constexpr int NB     = 8;
constexpr int NFIX   = 3000;
constexpr int NEWTON = 6;
constexpr int TPB    = 256;
constexpr int EPT    = 16;              // 300000 % 16 == 0
constexpr int EPB    = TPB * EPT;       // 4096
constexpr int NBX    = (DOF + EPB - 1) / EPB;   // 74 blocks per batch
constexpr int GRID   = NBX * NB;        // 592
constexpr int NACCL  = NEWTON * NB * 6; // 288 Gram acc lines per parity bank
constexpr int NPUBL  = NEWTON * NB;     // 48 pub lines per parity bank

// ---- static device scratch (no d_ws dependence; .bss zero-init at load) ----
__device__ float g_part[NEWTON][NB][NBX][8];   // fallback path only
__device__ float g_UW[NB * DOF];               // fallback path only

// acc line: u64, top byte = arrival count, low 56 bits = biased fixed-point
// sum (scale 2^20, per-add bias 2^44 so negative Gram entries encode safely;
// 64-add total: bias 2^50 + |sum|<2^48 stays clear of the count byte).
// pub line: 6 u64 words, each (tag<<32)|f32bits — tag+data in ONE atomic store.
struct alignas(64) PadU64 { u64 v; u64 pad[7]; };
struct alignas(64) PadPub { u64 q[8]; };
__device__ PadU64 g_acc[2][NEWTON][NB][6];
__device__ PadPub g_pub[2][NEWTON][NB];
__device__ u32    g_call;    // bumped once per call by block 0 at its finish

constexpr u64   CNT_ONE  = 1ull << 56;
constexpr u64   SUM_MASK = CNT_ONE - 1ull;
constexpr i64   ABIAS    = 1ll << 44;             // per-add bias
constexpr float FXS      = 1048576.0f;            // 2^20
constexpr float FXS_INV  = 9.5367431640625e-07f;  // 2^-20

__device__ __forceinline__ u16 f2b(float f) {   // f32 -> bf16 RNE
  u32 x = __float_as_uint(f);
  u32 r = x + 0x7fffu + ((x >> 16) & 1u);
  return (u16)(r >> 16);
}

template<bool BF>
__device__ __forceinline__ void load16(const void* p, long long off, float* dst) {
  if (BF) {
    const u16* b = (const u16*)p + off;
    uint4 a0 = *(const uint4*)(b);
    uint4 a1 = *(const uint4*)(b + 8);
    u32 w[8] = {a0.x, a0.y, a0.z, a0.w, a1.x, a1.y, a1.z, a1.w};
#pragma unroll
    for (int i = 0; i < 8; ++i) {
      dst[2*i]   = __uint_as_float((w[i] & 0xffffu) << 16);
      dst[2*i+1] = __uint_as_float(w[i] & 0xffff0000u);
    }
  } else {
    const float* b = (const float*)p + off;
#pragma unroll
    for (int i = 0; i < 4; ++i) {
      float4 v = *(const float4*)(b + 4*i);
      dst[4*i] = v.x; dst[4*i+1] = v.y; dst[4*i+2] = v.z; dst[4*i+3] = v.w;
    }
  }
}

template<bool BF>
__device__ __forceinline__ void store16(void* p, long long off, const float* src) {
  if (BF) {
    u16* b = (u16*)p + off;
    u32 w[8];
#pragma unroll
    for (int i = 0; i < 8; ++i)
      w[i] = (u32)f2b(src[2*i]) | ((u32)f2b(src[2*i+1]) << 16);
    *(uint4*)(b)     = make_uint4(w[0], w[1], w[2], w[3]);
    *(uint4*)(b + 8) = make_uint4(w[4], w[5], w[6], w[7]);
  } else {
    float* b = (float*)p + off;
#pragma unroll
    for (int i = 0; i < 4; ++i)
      *(float4*)(b + 4*i) = make_float4(src[4*i], src[4*i+1], src[4*i+2], src[4*i+3]);
  }
}

// dtype probe: k_diag in [1,2). bf16 -> every u16 in [0x3F80,0x4000]; f32 even
// words are random mantissa halves (false-positive p ~ 2e-22 over 8 words).
__device__ __forceinline__ bool probe_bf(const void* KD) {
  const u16* k = (const u16*)KD;
  bool bf = true;
#pragma unroll
  for (int i = 0; i < 8; ++i) {
    u16 v = k[2*i];
    bf = bf && (v >= 0x3F80u && v <= 0x4000u);
  }
  return bf;
}

// block-local fixed-dof mask: scan the 12 KB FIX list (L2-broadcast) into an
// LDS bitmask covering this block's 4096-dof window.
__device__ __forceinline__ u32 build_mask_bits(const int* __restrict__ FIX,
                                               int blk_base, int tid, u32* mw) {
  for (int i = tid; i < EPB / 32; i += TPB) mw[i] = 0u;
  __syncthreads();
  for (int i = tid; i < NFIX; i += TPB) {
    const int d = FIX[i] - blk_base;
    if (d >= 0 && d < EPB) atomicOr(&mw[d >> 5], 1u << (d & 31));
  }
  __syncthreads();
  const int off = tid * EPT;
  return (mw[off >> 5] >> (off & 31)) & 0xFFFFu;
}

// Gram-form partials: cr(a) = filt*(1+a) - P*a^2 - Q*a^3 with P=1.2*u*d^2,
// Q=0.4*d^3 (d = -filt/den; den*d = -filt makes the cubic exact). Then
// sum cr(a)^2 = quadratic form in (filt,P,Q): SIX sums G = {ff,fP,fQ,PP,PQ,QQ}
// cover init-norm^2 (=ff) AND all 6 trial norms (constant weights per alpha,
// applied after the reduction). Fixed dofs: filt=0 -> d=P=Q=0 -> no terms.
__device__ __forceinline__ void compute_gram(bool act, const float* u,
                                             const float* f, const float* kv,
                                             float* du, u32 mbits, float* G) {
#pragma unroll
  for (int j = 0; j < 6; ++j) G[j] = 0.0f;
  if (!act) {
#pragma unroll
    for (int e = 0; e < EPT; ++e) du[e] = 0.0f;
    return;
  }
#pragma unroll
  for (int e = 0; e < EPT; ++e) {
    const bool fr = ((mbits >> e) & 1u) == 0u;
    const float uu = u[e], ff = f[e], kk = kv[e];
    const float u2 = uu * uu;
    const float g    = fmaf(0.4f * u2, uu, kk * uu);     // grad_e
    const float filt = fr ? (ff - g) : 0.0f;             // free*(f - grad)
    const float den  = fmaf(1.2f, u2, kk);               // diag Hessian; 20-iter
    const float d    = -filt * __builtin_amdgcn_rcpf(den); // CG on diag == exact
    du[e] = d;
    const float d2 = d * d;
    const float P  = (1.2f * uu) * d2;
    const float Q  = (0.4f * d2) * d;
    G[0] = fmaf(filt, filt, G[0]);
    G[1] = fmaf(filt, P,    G[1]);
    G[2] = fmaf(filt, Q,    G[2]);
    G[3] = fmaf(P,    P,    G[3]);
    G[4] = fmaf(P,    Q,    G[4]);
    G[5] = fmaf(Q,    Q,    G[5]);
  }
}

// wave-shuffle + LDS reduce of this block's 6 Gram sums into sred[*][j]
__device__ __forceinline__ void block_reduce6(const float* G, int tid,
                                              float (*sred)[8]) {
  const int lane = tid & 63, wid = tid >> 6;
#pragma unroll
  for (int j = 0; j < 6; ++j) {
    float v = G[j];
#pragma unroll
    for (int off = 32; off > 0; off >>= 1) v += __shfl_down(v, off, 64);
    if (lane == 0) sred[wid][j] = v;
  }
  __syncthreads();
}

// alpha pick from 6 Gram sums: norms^2(a) = s^2*ff - 2sa^2*fP - 2sa^3*fQ
//                                         + a^4*PP + 2a^5*PQ + a^6*QQ, s=1+a.
// Compare squared (sqrt monotonic). ALPHA_MIN fallback == trials 5..7.
__device__ __forceinline__ int pick_idx(const float* G) {
  const float AL[6] = {1.0f, 0.5f, 0.25f, 0.125f, 0.0625f, 0.05f};
  int idx = 5;
  bool found = false;
#pragma unroll
  for (int t = 0; t < 6; ++t) {
    const float a = AL[t], s = 1.0f + a, a2 = a * a;
    const float n2 = s * s * G[0] - 2.0f * s * a2 * G[1] - 2.0f * s * a2 * a * G[2]
                   + a2 * a2 * G[3] + 2.0f * a2 * a2 * a * G[4]
                   + a2 * a2 * a2 * G[5];
    if (!found && n2 < G[0]) { idx = t; found = true; }
  }
  return idx;
}

// fallback-path tree reduce + pick (old 7-norm scheme, proven)
__device__ __forceinline__ float sum_pick(float (*red)[8], int n, int b, int tid) {
  if (tid < NBX) {
#pragma unroll
    for (int j = 0; j < 7; ++j)
      red[tid][j] = __hip_atomic_load(&g_part[n][b][tid][j], __ATOMIC_RELAXED,
                                      __HIP_MEMORY_SCOPE_AGENT);
  }
  __syncthreads();
#pragma unroll
  for (int s = 64; s >= 1; s >>= 1) {
    if (tid < s && tid + s < NBX) {
#pragma unroll
      for (int j = 0; j < 7; ++j) red[tid][j] += red[tid + s][j];
    }
    __syncthreads();
  }
  const float initn = sqrtf(red[0][0]);
  const float AL[6] = {1.0f, 0.5f, 0.25f, 0.125f, 0.0625f, 0.05f};
  float ab = 0.05f;
  bool found = false;
#pragma unroll
  for (int t = 0; t < 6; ++t) {
    const float nt = sqrtf(red[0][1 + t]);
    if (!found && nt < initn) { ab = AL[t]; found = true; }
  }
  __syncthreads();
  return ab;
}

// old-style 7 partials (fallback path only; bitwise-stable decisions there)
__device__ __forceinline__ void compute_partials7(bool act, const float* u,
                                                  const float* f, const float* kv,
                                                  float* du, u32 mbits, float* part) {
#pragma unroll
  for (int j = 0; j < 7; ++j) part[j] = 0.0f;
  const float AL[6] = {1.0f, 0.5f, 0.25f, 0.125f, 0.0625f, 0.05f};
  if (!act) {
#pragma unroll
    for (int e = 0; e < EPT; ++e) du[e] = 0.0f;
    return;
  }
#pragma unroll
  for (int e = 0; e < EPT; ++e) {
    const bool fr = ((mbits >> e) & 1u) == 0u;
    const float uu = u[e], ff = f[e], kk = kv[e];
    const float u2 = uu * uu;
    const float g    = fmaf(0.4f * u2, uu, kk * uu);
    const float filt = fr ? (ff - g) : 0.0f;
    part[0] = fmaf(filt, filt, part[0]);
    const float den = fmaf(1.2f, u2, kk);
    const float d   = -filt * __builtin_amdgcn_rcpf(den);
    du[e] = d;
    const float d2  = d * d;
    const float Bc  = 1.2f * uu * d2;
    const float Cc  = 0.4f * d2 * d;
#pragma unroll
    for (int t = 0; t < 6; ++t) {
      const float a  = AL[t];
      const float cr = fmaf(a, fmaf(a, fmaf(-Cc, a, -Bc), filt), filt);
      part[1 + t] = fmaf(cr, cr, part[1 + t]);
    }
  }
}

// ================= cooperative single-dispatch path =================
// Per iteration (round-12 sync shape, 6 Gram lines instead of 7 norm lines):
//   1. lanes 0-5 fetch_add (1<<56)|(q+2^44) into the per-(n,b,j) acc lines:
//      the add IS arrival + reduction; bias makes negative entries safe.
//   2. the lane whose RMW returns count 63 decodes the final biased sum and
//      stores (tag<<32)|f32 as ONE u64 into word j of the per-(n,b) pub line.
//   3. tid0 polls the single pub line (6 u64, sleep(8) — proven config); all
//      tags match -> pick alpha locally. Integer sums -> deterministic.
__global__ void __launch_bounds__(TPB, 3) k_coop(const void* __restrict__ F,
                                                 const void* __restrict__ U0,
                                                 const void* __restrict__ KD,
                                                 const int* __restrict__ FIX,
                                                 void* __restrict__ OUT) {
  const int tid = threadIdx.x, bid = blockIdx.x;
  const int b = bid / NBX, bx = bid - b * NBX;
  const int d0 = bx * EPB + tid * EPT;
  const bool act = (d0 < DOF);
  const long long gb = (long long)b * DOF + d0;
  const bool bf = probe_bf(KD);
  const float ALTAB[8] = {1.0f, 0.5f, 0.25f, 0.125f, 0.0625f, 0.05f, 0.05f, 0.05f};

  __shared__ u32   mw[EPB / 32];
  __shared__ float sred[TPB / 64][8];
  __shared__ float salpha[2];

  // parity select (previous call's bump visible via the dispatch boundary)
  const u32 call = __hip_atomic_load(&g_call, __ATOMIC_RELAXED,
                                     __HIP_MEMORY_SCOPE_AGENT);
  const int par  = (int)(call & 1u);

  // prefetch inputs FIRST: overlap HBM latency with bank-reset + mask build
  float u[EPT], f[EPT], kv[EPT], du[EPT];
  if (act) {
    if (bf) { load16<true >(U0, gb, u); load16<true >(F, gb, f); load16<true >(KD, d0, kv); }
    else    { load16<false>(U0, gb, u); load16<false>(F, gb, f); load16<false>(KD, d0, kv); }
  }

  // zero the OTHER parity bank for the next call (untouched this call)
  if (tid == 0 && bid < NACCL) {
    const int n2 = bid / (NB * 6), r = bid % (NB * 6);
    __hip_atomic_store(&g_acc[par ^ 1][n2][r / 6][r % 6].v, 0ull,
                       __ATOMIC_RELAXED, __HIP_MEMORY_SCOPE_AGENT);
  }
  if (bid >= NACCL && bid < NACCL + NPUBL && tid < 8) {
    const int pl = bid - NACCL;
    __hip_atomic_store(&g_pub[par ^ 1][pl / NB][pl % NB].q[tid], 0ull,
                       __ATOMIC_RELAXED, __HIP_MEMORY_SCOPE_AGENT);
  }

  const u32 mbits = build_mask_bits(FIX, bx * EPB, tid, mw);

  for (int n = 0; n < NEWTON; ++n) {
    const u32 tag = call * 8u + (u32)n + 1u;   // unique vs any stale bank content
    float G[6];
    compute_gram(act, u, f, kv, du, mbits, G);
    block_reduce6(G, tid, sred);              // ends with __syncthreads
    if (tid < 6) {                            // add == arrival == reduction
      const float s = sred[0][tid] + sred[1][tid] + sred[2][tid] + sred[3][tid];
      const i64  q  = (i64)(s * FXS);         // |q| < 2^42 per block
      const u64 enc = (u64)(q + ABIAS);       // bits [0,45) only
      const u64 old = __hip_atomic_fetch_add(&g_acc[par][n][b][tid].v,
                                             CNT_ONE | enc,
                                             __ATOMIC_RELAXED,
                                             __HIP_MEMORY_SCOPE_AGENT);
      if ((old >> 56) == (u64)(NBX - 1)) {    // I'm the last adder of line tid
        const i64 fin = (i64)((old & SUM_MASK) + enc) - (i64)NBX * ABIAS;
        const float fl = (float)fin * FXS_INV;
        const u64 pv = ((u64)tag << 32) | (u64)__float_as_uint(fl);
        __hip_atomic_store(&g_pub[par][n][b].q[tid], pv,
                           __ATOMIC_RELAXED, __HIP_MEMORY_SCOPE_AGENT);
      }
    }
    if (tid == 0) {                           // single-line poll, 74 pollers
      u64 v[6];
      for (;;) {
        bool ok = true;
#pragma unroll
        for (int j = 0; j < 6; ++j)
          v[j] = __hip_atomic_load(&g_pub[par][n][b].q[j], __ATOMIC_RELAXED,
                                   __HIP_MEMORY_SCOPE_AGENT);
#pragma unroll
        for (int j = 0; j < 6; ++j) ok = ok && ((u32)(v[j] >> 32) == tag);
        if (ok) break;
        __builtin_amdgcn_s_sleep(8);          // ~0.2us backoff (proven)
      }
      float Gs[6];
#pragma unroll
      for (int j = 0; j < 6; ++j) Gs[j] = __uint_as_float((u32)v[j]);
      salpha[n & 1] = ALTAB[pick_idx(Gs)];
    }
    __syncthreads();                          // alpha broadcast
    const float ab = salpha[n & 1];
    if (act) {
#pragma unroll
      for (int e = 0; e < EPT; ++e) u[e] = fmaf(ab, du[e], u[e]);
    }
    // no trailing sync: block_reduce6's sync guards sred; salpha parity-buffered
  }

  if (bid == 0 && tid == 0)                   // single bump after b0's finish
    __hip_atomic_store(&g_call, call + 1u, __ATOMIC_RELAXED,
                       __HIP_MEMORY_SCOPE_AGENT);

  if (act) {
    if (bf) store16<true >(OUT, gb, u);
    else    store16<false>(OUT, gb, u);
  }
}

// ============ fallback multi-kernel path (old proven scheme) ============
template<bool BF>
__device__ __forceinline__ void load_state(const void* U0, const void* F, const void* KD,
                                           int n, long long gb, int d0,
                                           float* u, float* f, float* kv) {
  if (n == 0) load16<BF>(U0, gb, u);
  else {
#pragma unroll
    for (int i = 0; i < 4; ++i) {
      float4 q = *(const float4*)(g_UW + gb + 4*i);
      u[4*i] = q.x; u[4*i+1] = q.y; u[4*i+2] = q.z; u[4*i+3] = q.w;
    }
  }
  load16<BF>(F, gb, f);
  load16<BF>(KD, d0, kv);
}

__global__ void __launch_bounds__(TPB) k_part_fb(const void* __restrict__ F,
                                                 const void* __restrict__ U0,
                                                 const void* __restrict__ KD,
                                                 const int* __restrict__ FIX, int n) {
  const int tid = threadIdx.x, bid = blockIdx.x;
  const int b = bid / NBX, bx = bid - b * NBX;
  const int d0 = bx * EPB + tid * EPT;
  const bool act = (d0 < DOF);
  const long long gb = (long long)b * DOF + d0;
  const bool bf = probe_bf(KD);
  __shared__ u32   mw[EPB / 32];
  __shared__ float sred[TPB / 64][8];
  const u32 mbits = build_mask_bits(FIX, bx * EPB, tid, mw);
  float u[EPT], f[EPT], kv[EPT], du[EPT];
  if (act) {
    if (bf) load_state<true >(U0, F, KD, n, gb, d0, u, f, kv);
    else    load_state<false>(U0, F, KD, n, gb, d0, u, f, kv);
  }
  float part[7];
  compute_partials7(act, u, f, kv, du, mbits, part);
  const int lane = tid & 63, wid = tid >> 6;
#pragma unroll
  for (int j = 0; j < 7; ++j) {
    float v = part[j];
#pragma unroll
    for (int off = 32; off > 0; off >>= 1) v += __shfl_down(v, off, 64);
    if (lane == 0) sred[wid][j] = v;
  }
  __syncthreads();
  if (tid < 7)
    g_part[n][b][bx][tid] = sred[0][tid] + sred[1][tid] + sred[2][tid] + sred[3][tid];
}

__global__ void __launch_bounds__(TPB) k_upd_fb(const void* __restrict__ F,
                                                const void* __restrict__ U0,
                                                const void* __restrict__ KD,
                                                const int* __restrict__ FIX,
                                                void* __restrict__ OUT, int n, int last) {
  const int tid = threadIdx.x, bid = blockIdx.x;
  const int b = bid / NBX, bx = bid - b * NBX;
  const int d0 = bx * EPB + tid * EPT;
  const bool act = (d0 < DOF);
  const long long gb = (long long)b * DOF + d0;
  const bool bf = probe_bf(KD);
  __shared__ u32   mw[EPB / 32];
  __shared__ float red[80][8];
  const u32 mbits = build_mask_bits(FIX, bx * EPB, tid, mw);
  const float ab = sum_pick(red, n, b, tid);
  if (!act) return;
  float u[EPT], f[EPT], kv[EPT], du[EPT];
  if (bf) load_state<true >(U0, F, KD, n, gb, d0, u, f, kv);
  else    load_state<false>(U0, F, KD, n, gb, d0, u, f, kv);
  float part[7];
  compute_partials7(act, u, f, kv, du, mbits, part);   // recompute du
#pragma unroll
  for (int e = 0; e < EPT; ++e) u[e] = fmaf(ab, du[e], u[e]);
#pragma unroll
  for (int i = 0; i < 4; ++i)
    *(float4*)(g_UW + gb + 4*i) = make_float4(u[4*i], u[4*i+1], u[4*i+2], u[4*i+3]);
  if (last) {
    if (bf) store16<true >(OUT, gb, u);
    else    store16<false>(OUT, gb, u);
  }
}

extern "C" void kernel_launch(void* const* d_in, const int* in_sizes, int n_in,
                              void* d_out, int out_size, void* d_ws, size_t ws_size,
                              hipStream_t stream) {
  const void* F   = d_in[0];               // external_forces [B, DOF]
  const void* U0  = d_in[1];               // u0              [B, DOF]
  const void* KD  = d_in[2];               // k_diag          [DOF]
  const int*  FIX = (const int*)d_in[3];   // fixed_dofs      [NFIX] int32
  void* OUT = d_out;

  void* args[] = {(void*)&F, (void*)&U0, (void*)&KD, (void*)&FIX, (void*)&OUT};
  hipError_t e = hipLaunchCooperativeKernel((void*)k_coop, dim3(GRID), dim3(TPB),
                                            args, 0, stream);
  if (e != hipSuccess) {
    (void)hipGetLastError();               // clear sticky error, take fallback
    for (int n = 0; n < NEWTON; ++n) {
      k_part_fb<<<GRID, TPB, 0, stream>>>(F, U0, KD, FIX, n);
      k_upd_fb<<<GRID, TPB, 0, stream>>>(F, U0, KD, FIX, d_out, n,
                                         (n == NEWTON - 1) ? 1 : 0);
    }
  }
}

// Round 14
// 129.149 us; speedup vs baseline: 1.0525x; 1.0525x over previous
//
#include <hip/hip_runtime.h>

typedef unsigned short u16;
typedef unsigned int   u32;
typedef unsigned long long u64;
typedef long long i64;

constexpr int DOF    = 300000;
constexpr int NB     = 8;
constexpr int NFIX   = 3000;
constexpr int NEWTON = 6;

// ---- cooperative config: 240 blocks x 512 thr x 20 elem = 1 block/CU ----
constexpr int CTPB  = 512;
constexpr int CEPT  = 20;
constexpr int CEPB  = CTPB * CEPT;                 // 10240
constexpr int CNBX  = (DOF + CEPB - 1) / CEPB;     // 30 blocks per batch
constexpr int CGRID = CNBX * NB;                   // 240
constexpr int NACCL = NEWTON * NB * 6;             // 288 acc lines per bank

// ---- fallback config (proven multi-kernel shape) ----
constexpr int FTPB  = 256;
constexpr int FEPT  = 16;
constexpr int FEPB  = FTPB * FEPT;                 // 4096
constexpr int FNBX  = (DOF + FEPB - 1) / FEPB;     // 74
constexpr int FGRID = FNBX * NB;                   // 592

// ---- static device scratch (no d_ws dependence; .bss zero-init) ----
__device__ float g_part[NEWTON][NB][FNBX][8];      // fallback only
__device__ float g_UW[NB * DOF];                   // fallback only

// acc line: u64, top byte = arrival count, low 56 = biased fixed-point sum
// (scale 2^20, per-add bias 2^44; 30 adds: bias 30*2^44 + |sum| << 2^56).
// pub line: 6 u64 words (tag<<32)|f32 — tag+data atomic, self-validating
// (tags globally unique across calls -> no zeroing, no parity needed).
struct alignas(64) PadU64 { u64 v; u64 pad[7]; };
struct alignas(64) PadPub { u64 q[8]; };
__device__ PadU64 g_acc[2][NEWTON][NB][6];         // parity-banked (counts)
__device__ PadPub g_pub[NEWTON][NB];               // single bank (tag-matched)
__device__ PadU64 g_done[2];                       // parity-banked finish count
__device__ u32    g_call;                          // bumped after ALL blocks done

constexpr u64   CNT_ONE  = 1ull << 56;
constexpr u64   SUM_MASK = CNT_ONE - 1ull;
constexpr i64   ABIAS    = 1ll << 44;
constexpr float FXS      = 1048576.0f;             // 2^20
constexpr float FXS_INV  = 9.5367431640625e-07f;   // 2^-20

__device__ __forceinline__ u16 f2b(float f) {      // f32 -> bf16 RNE
  u32 x = __float_as_uint(f);
  u32 r = x + 0x7fffu + ((x >> 16) & 1u);
  return (u16)(r >> 16);
}

// ---- 20-elem vector load/store (coop path). f32: 5x float4 (80B-aligned);
// bf16: 5x uint2 (40B offsets are 8B-aligned). ----
template<bool BF>
__device__ __forceinline__ void load20(const void* p, long long off, float* dst) {
  if (BF) {
    const u16* b = (const u16*)p + off;
#pragma unroll
    for (int i = 0; i < 5; ++i) {
      uint2 a = *(const uint2*)(b + 4*i);
      u32 w0 = a.x, w1 = a.y;
      dst[4*i]   = __uint_as_float((w0 & 0xffffu) << 16);
      dst[4*i+1] = __uint_as_float(w0 & 0xffff0000u);
      dst[4*i+2] = __uint_as_float((w1 & 0xffffu) << 16);
      dst[4*i+3] = __uint_as_float(w1 & 0xffff0000u);
    }
  } else {
    const float* b = (const float*)p + off;
#pragma unroll
    for (int i = 0; i < 5; ++i) {
      float4 v = *(const float4*)(b + 4*i);
      dst[4*i] = v.x; dst[4*i+1] = v.y; dst[4*i+2] = v.z; dst[4*i+3] = v.w;
    }
  }
}

template<bool BF>
__device__ __forceinline__ void store20(void* p, long long off, const float* src) {
  if (BF) {
    u16* b = (u16*)p + off;
#pragma unroll
    for (int i = 0; i < 5; ++i) {
      u32 w0 = (u32)f2b(src[4*i])   | ((u32)f2b(src[4*i+1]) << 16);
      u32 w1 = (u32)f2b(src[4*i+2]) | ((u32)f2b(src[4*i+3]) << 16);
      *(uint2*)(b + 4*i) = make_uint2(w0, w1);
    }
  } else {
    float* b = (float*)p + off;
#pragma unroll
    for (int i = 0; i < 5; ++i)
      *(float4*)(b + 4*i) = make_float4(src[4*i], src[4*i+1], src[4*i+2], src[4*i+3]);
  }
}

// 16-elem versions (fallback path)
template<bool BF>
__device__ __forceinline__ void load16(const void* p, long long off, float* dst) {
  if (BF) {
    const u16* b = (const u16*)p + off;
    uint4 a0 = *(const uint4*)(b);
    uint4 a1 = *(const uint4*)(b + 8);
    u32 w[8] = {a0.x, a0.y, a0.z, a0.w, a1.x, a1.y, a1.z, a1.w};
#pragma unroll
    for (int i = 0; i < 8; ++i) {
      dst[2*i]   = __uint_as_float((w[i] & 0xffffu) << 16);
      dst[2*i+1] = __uint_as_float(w[i] & 0xffff0000u);
    }
  } else {
    const float* b = (const float*)p + off;
#pragma unroll
    for (int i = 0; i < 4; ++i) {
      float4 v = *(const float4*)(b + 4*i);
      dst[4*i] = v.x; dst[4*i+1] = v.y; dst[4*i+2] = v.z; dst[4*i+3] = v.w;
    }
  }
}

template<bool BF>
__device__ __forceinline__ void store16(void* p, long long off, const float* src) {
  if (BF) {
    u16* b = (u16*)p + off;
    u32 w[8];
#pragma unroll
    for (int i = 0; i < 8; ++i)
      w[i] = (u32)f2b(src[2*i]) | ((u32)f2b(src[2*i+1]) << 16);
    *(uint4*)(b)     = make_uint4(w[0], w[1], w[2], w[3]);
    *(uint4*)(b + 8) = make_uint4(w[4], w[5], w[6], w[7]);
  } else {
    float* b = (float*)p + off;
#pragma unroll
    for (int i = 0; i < 4; ++i)
      *(float4*)(b + 4*i) = make_float4(src[4*i], src[4*i+1], src[4*i+2], src[4*i+3]);
  }
}

// dtype probe: k_diag in [1,2). bf16 -> every u16 in [0x3F80,0x4000]; f32 even
// words are random mantissa halves (false-positive p ~ 2e-22 over 8 words).
__device__ __forceinline__ bool probe_bf(const void* KD) {
  const u16* k = (const u16*)KD;
  bool bf = true;
#pragma unroll
  for (int i = 0; i < 8; ++i) {
    u16 v = k[2*i];
    bf = bf && (v >= 0x3F80u && v <= 0x4000u);
  }
  return bf;
}

// Gram-form partials (NE elems/thread): cr(a) = filt*(1+a) - P*a^2 - Q*a^3,
// P=1.2*u*d^2, Q=0.4*d^3, d = -filt/den (exact cubic since den*d = -filt).
// sum cr(a)^2 is a quadratic form in (filt,P,Q) -> 6 sums cover init-norm^2
// and all 6 trial norms. Fixed dofs: filt=0 -> d=P=Q=0.
template<int NE>
__device__ __forceinline__ void compute_gram(bool act, const float* u,
                                             const float* f, const float* kv,
                                             float* du, u32 mbits, float* G) {
#pragma unroll
  for (int j = 0; j < 6; ++j) G[j] = 0.0f;
  if (!act) {
#pragma unroll
    for (int e = 0; e < NE; ++e) du[e] = 0.0f;
    return;
  }
#pragma unroll
  for (int e = 0; e < NE; ++e) {
    const bool fr = ((mbits >> e) & 1u) == 0u;
    const float uu = u[e], ff = f[e], kk = kv[e];
    const float u2 = uu * uu;
    const float g    = fmaf(0.4f * u2, uu, kk * uu);
    const float filt = fr ? (ff - g) : 0.0f;
    const float den  = fmaf(1.2f, u2, kk);
    const float d    = -filt * __builtin_amdgcn_rcpf(den);
    du[e] = d;
    const float d2 = d * d;
    const float P  = (1.2f * uu) * d2;
    const float Q  = (0.4f * d2) * d;
    G[0] = fmaf(filt, filt, G[0]);
    G[1] = fmaf(filt, P,    G[1]);
    G[2] = fmaf(filt, Q,    G[2]);
    G[3] = fmaf(P,    P,    G[3]);
    G[4] = fmaf(P,    Q,    G[4]);
    G[5] = fmaf(Q,    Q,    G[5]);
  }
}

// alpha pick from 6 Gram sums (compare squared; fallback idx 5 == 0.05)
__device__ __forceinline__ int pick_idx(const float* G) {
  const float AL[6] = {1.0f, 0.5f, 0.25f, 0.125f, 0.0625f, 0.05f};
  int idx = 5;
  bool found = false;
#pragma unroll
  for (int t = 0; t < 6; ++t) {
    const float a = AL[t], s = 1.0f + a, a2 = a * a;
    const float n2 = s * s * G[0] - 2.0f * s * a2 * G[1] - 2.0f * s * a2 * a * G[2]
                   + a2 * a2 * G[3] + 2.0f * a2 * a2 * a * G[4]
                   + a2 * a2 * a2 * G[5];
    if (!found && n2 < G[0]) { idx = t; found = true; }
  }
  return idx;
}

// ================= cooperative single-dispatch path =================
// Sync per iteration (round-12's proven shape, 30 arrivals/line, 1 blk/CU):
//   lanes 0-5 fetch_add (1<<56)|(q+2^44) -> add IS arrival+reduction; the
//   lane seeing count CNBX-1 publishes (tag<<32)|f32 into ONE pub line;
//   tid0 polls that line (s_sleep(8)); alpha picked locally, deterministic.
__global__ void __launch_bounds__(CTPB, 2) k_coop(const void* __restrict__ F,
                                                  const void* __restrict__ U0,
                                                  const void* __restrict__ KD,
                                                  const int* __restrict__ FIX,
                                                  void* __restrict__ OUT) {
  const int tid = threadIdx.x, bid = blockIdx.x;
  const int b = bid / CNBX, bx = bid - b * CNBX;
  const int d0 = bx * CEPB + tid * CEPT;
  const bool act = (d0 + CEPT <= DOF);      // blocks are full-vec or inactive
  const long long gb = (long long)b * DOF + d0;
  const bool bf = probe_bf(KD);
  const float ALTAB[8] = {1.0f, 0.5f, 0.25f, 0.125f, 0.0625f, 0.05f, 0.05f, 0.05f};

  __shared__ u32   mw[CEPB / 32 + 1];       // +1 pad word for 20-bit extraction
  __shared__ float sred[CTPB / 64][8];
  __shared__ float salpha[2];

  // parity select; previous call fully retired (stream-serialized), so its
  // g_call bump is visible via the dispatch boundary.
  const u32 call = __hip_atomic_load(&g_call, __ATOMIC_RELAXED,
                                     __HIP_MEMORY_SCOPE_AGENT);
  const int par  = (int)(call & 1u);

  // prefetch inputs first: overlap HBM latency with resets + mask build
  float u[CEPT], f[CEPT], kv[CEPT], du[CEPT];
  if (act) {
    if (bf) { load20<true >(U0, gb, u); load20<true >(F, gb, f); load20<true >(KD, d0, kv); }
    else    { load20<false>(U0, gb, u); load20<false>(F, gb, f); load20<false>(KD, d0, kv); }
  }

  // zero the OTHER acc parity bank (its last user, call-1, fully retired) and
  // the other done bank. Pub lines need no reset (tag-validated).
  if (tid == 0) {
    for (int L = bid; L < NACCL; L += CGRID) {
      const int n2 = L / (NB * 6), r = L % (NB * 6);
      __hip_atomic_store(&g_acc[par ^ 1][n2][r / 6][r % 6].v, 0ull,
                         __ATOMIC_RELAXED, __HIP_MEMORY_SCOPE_AGENT);
    }
    if (bid == 0)
      __hip_atomic_store(&g_done[par ^ 1].v, 0ull,
                         __ATOMIC_RELAXED, __HIP_MEMORY_SCOPE_AGENT);
  }

  // block-local fixed-dof bitmask over this block's 10240-dof window
  for (int i = tid; i < CEPB / 32 + 1; i += CTPB) mw[i] = 0u;
  __syncthreads();
  const int blk_base = bx * CEPB;
  for (int i = tid; i < NFIX; i += CTPB) {
    const int d = FIX[i] - blk_base;
    if (d >= 0 && d < CEPB) atomicOr(&mw[d >> 5], 1u << (d & 31));
  }
  __syncthreads();
  const int off = tid * CEPT;                // 20 bits, may span 2 words
  const u64 mm = (((u64)mw[(off >> 5) + 1] << 32) | (u64)mw[off >> 5]) >> (off & 31);
  const u32 mbits = (u32)mm & 0xFFFFFu;

  for (int n = 0; n < NEWTON; ++n) {
    const u32 tag = call * 8u + (u32)n + 1u; // globally unique, never stale-matches
    float G[6];
    compute_gram<CEPT>(act, u, f, kv, du, mbits, G);
    { // 8-wave block reduce into sred[*][j]
      const int lane = tid & 63, wid = tid >> 6;
#pragma unroll
      for (int j = 0; j < 6; ++j) {
        float v = G[j];
#pragma unroll
        for (int o = 32; o > 0; o >>= 1) v += __shfl_down(v, o, 64);
        if (lane == 0) sred[wid][j] = v;
      }
      __syncthreads();
    }
    if (tid < 6) {                           // add == arrival == reduction
      float s = sred[0][tid];
#pragma unroll
      for (int w2 = 1; w2 < CTPB / 64; ++w2) s += sred[w2][tid];
      const i64 q   = (i64)(s * FXS);        // |q| < 2^43 per block
      const u64 enc = (u64)(q + ABIAS);
      const u64 old = __hip_atomic_fetch_add(&g_acc[par][n][b][tid].v,
                                             CNT_ONE | enc, __ATOMIC_RELAXED,
                                             __HIP_MEMORY_SCOPE_AGENT);
      if ((old >> 56) == (u64)(CNBX - 1)) {  // last adder of line tid
        const i64 fin = (i64)((old & SUM_MASK) + enc) - (i64)CNBX * ABIAS;
        const float fl = (float)fin * FXS_INV;
        __hip_atomic_store(&g_pub[n][b].q[tid],
                           ((u64)tag << 32) | (u64)__float_as_uint(fl),
                           __ATOMIC_RELAXED, __HIP_MEMORY_SCOPE_AGENT);
      }
    }
    if (tid == 0) {                          // single-line poll, 30 pollers
      u64 v[6];
      for (;;) {
        bool ok = true;
#pragma unroll
        for (int j = 0; j < 6; ++j)
          v[j] = __hip_atomic_load(&g_pub[n][b].q[j], __ATOMIC_RELAXED,
                                   __HIP_MEMORY_SCOPE_AGENT);
#pragma unroll
        for (int j = 0; j < 6; ++j) ok = ok && ((u32)(v[j] >> 32) == tag);
        if (ok) break;
        __builtin_amdgcn_s_sleep(8);         // proven backoff
      }
      float Gs[6];
#pragma unroll
      for (int j = 0; j < 6; ++j) Gs[j] = __uint_as_float((u32)v[j]);
      salpha[n & 1] = ALTAB[pick_idx(Gs)];
    }
    __syncthreads();                         // alpha broadcast
    const float ab = salpha[n & 1];
    if (act) {
#pragma unroll
      for (int e = 0; e < CEPT; ++e) u[e] = fmaf(ab, du[e], u[e]);
    }
  }

  if (act) {
    if (bf) store20<true >(OUT, gb, u);
    else    store20<false>(OUT, gb, u);
  }

  // g_call bump gated on ALL 240 blocks finishing (fixes the latent race of
  // rounds 11-13 where block 0 bumped after only batch-0 completion).
  if (tid == 0) {
    const u64 old = __hip_atomic_fetch_add(&g_done[par].v, 1ull,
                                           __ATOMIC_RELAXED,
                                           __HIP_MEMORY_SCOPE_AGENT);
    if (old == (u64)(CGRID - 1))
      __hip_atomic_store(&g_call, call + 1u, __ATOMIC_RELAXED,
                         __HIP_MEMORY_SCOPE_AGENT);
  }
}

// ============ fallback multi-kernel path (proven 256/16/74 shape) ============
__device__ __forceinline__ u32 build_mask_fb(const int* __restrict__ FIX,
                                             int blk_base, int tid, u32* mw) {
  for (int i = tid; i < FEPB / 32; i += FTPB) mw[i] = 0u;
  __syncthreads();
  for (int i = tid; i < NFIX; i += FTPB) {
    const int d = FIX[i] - blk_base;
    if (d >= 0 && d < FEPB) atomicOr(&mw[d >> 5], 1u << (d & 31));
  }
  __syncthreads();
  const int off = tid * FEPT;
  return (mw[off >> 5] >> (off & 31)) & 0xFFFFu;
}

__device__ __forceinline__ void compute_partials7(bool act, const float* u,
                                                  const float* f, const float* kv,
                                                  float* du, u32 mbits, float* part) {
#pragma unroll
  for (int j = 0; j < 7; ++j) part[j] = 0.0f;
  const float AL[6] = {1.0f, 0.5f, 0.25f, 0.125f, 0.0625f, 0.05f};
  if (!act) {
#pragma unroll
    for (int e = 0; e < FEPT; ++e) du[e] = 0.0f;
    return;
  }
#pragma unroll
  for (int e = 0; e < FEPT; ++e) {
    const bool fr = ((mbits >> e) & 1u) == 0u;
    const float uu = u[e], ff = f[e], kk = kv[e];
    const float u2 = uu * uu;
    const float g    = fmaf(0.4f * u2, uu, kk * uu);
    const float filt = fr ? (ff - g) : 0.0f;
    part[0] = fmaf(filt, filt, part[0]);
    const float den = fmaf(1.2f, u2, kk);
    const float d   = -filt * __builtin_amdgcn_rcpf(den);
    du[e] = d;
    const float d2  = d * d;
    const float Bc  = 1.2f * uu * d2;
    const float Cc  = 0.4f * d2 * d;
#pragma unroll
    for (int t = 0; t < 6; ++t) {
      const float a  = AL[t];
      const float cr = fmaf(a, fmaf(a, fmaf(-Cc, a, -Bc), filt), filt);
      part[1 + t] = fmaf(cr, cr, part[1 + t]);
    }
  }
}

__device__ __forceinline__ float sum_pick_fb(float (*red)[8], int n, int b, int tid) {
  if (tid < FNBX) {
#pragma unroll
    for (int j = 0; j < 7; ++j)
      red[tid][j] = __hip_atomic_load(&g_part[n][b][tid][j], __ATOMIC_RELAXED,
                                      __HIP_MEMORY_SCOPE_AGENT);
  }
  __syncthreads();
#pragma unroll
  for (int s = 64; s >= 1; s >>= 1) {
    if (tid < s && tid + s < FNBX) {
#pragma unroll
      for (int j = 0; j < 7; ++j) red[tid][j] += red[tid + s][j];
    }
    __syncthreads();
  }
  const float initn = sqrtf(red[0][0]);
  const float AL[6] = {1.0f, 0.5f, 0.25f, 0.125f, 0.0625f, 0.05f};
  float ab = 0.05f;
  bool found = false;
#pragma unroll
  for (int t = 0; t < 6; ++t) {
    const float nt = sqrtf(red[0][1 + t]);
    if (!found && nt < initn) { ab = AL[t]; found = true; }
  }
  __syncthreads();
  return ab;
}

template<bool BF>
__device__ __forceinline__ void load_state_fb(const void* U0, const void* F,
                                              const void* KD, int n, long long gb,
                                              int d0, float* u, float* f, float* kv) {
  if (n == 0) load16<BF>(U0, gb, u);
  else {
#pragma unroll
    for (int i = 0; i < 4; ++i) {
      float4 q = *(const float4*)(g_UW + gb + 4*i);
      u[4*i] = q.x; u[4*i+1] = q.y; u[4*i+2] = q.z; u[4*i+3] = q.w;
    }
  }
  load16<BF>(F, gb, f);
  load16<BF>(KD, d0, kv);
}

__global__ void __launch_bounds__(FTPB) k_part_fb(const void* __restrict__ F,
                                                  const void* __restrict__ U0,
                                                  const void* __restrict__ KD,
                                                  const int* __restrict__ FIX, int n) {
  const int tid = threadIdx.x, bid = blockIdx.x;
  const int b = bid / FNBX, bx = bid - b * FNBX;
  const int d0 = bx * FEPB + tid * FEPT;
  const bool act = (d0 < DOF);
  const long long gb = (long long)b * DOF + d0;
  const bool bf = probe_bf(KD);
  __shared__ u32   mw[FEPB / 32];
  __shared__ float sred[FTPB / 64][8];
  const u32 mbits = build_mask_fb(FIX, bx * FEPB, tid, mw);
  float u[FEPT], f[FEPT], kv[FEPT], du[FEPT];
  if (act) {
    if (bf) load_state_fb<true >(U0, F, KD, n, gb, d0, u, f, kv);
    else    load_state_fb<false>(U0, F, KD, n, gb, d0, u, f, kv);
  }
  float part[7];
  compute_partials7(act, u, f, kv, du, mbits, part);
  const int lane = tid & 63, wid = tid >> 6;
#pragma unroll
  for (int j = 0; j < 7; ++j) {
    float v = part[j];
#pragma unroll
    for (int o = 32; o > 0; o >>= 1) v += __shfl_down(v, o, 64);
    if (lane == 0) sred[wid][j] = v;
  }
  __syncthreads();
  if (tid < 7)
    g_part[n][b][bx][tid] = sred[0][tid] + sred[1][tid] + sred[2][tid] + sred[3][tid];
}

__global__ void __launch_bounds__(FTPB) k_upd_fb(const void* __restrict__ F,
                                                 const void* __restrict__ U0,
                                                 const void* __restrict__ KD,
                                                 const int* __restrict__ FIX,
                                                 void* __restrict__ OUT, int n, int last) {
  const int tid = threadIdx.x, bid = blockIdx.x;
  const int b = bid / FNBX, bx = bid - b * FNBX;
  const int d0 = bx * FEPB + tid * FEPT;
  const bool act = (d0 < DOF);
  const long long gb = (long long)b * DOF + d0;
  const bool bf = probe_bf(KD);
  __shared__ u32   mw[FEPB / 32];
  __shared__ float red[80][8];
  const u32 mbits = build_mask_fb(FIX, bx * FEPB, tid, mw);
  const float ab = sum_pick_fb(red, n, b, tid);
  if (!act) return;
  float u[FEPT], f[FEPT], kv[FEPT], du[FEPT];
  if (bf) load_state_fb<true >(U0, F, KD, n, gb, d0, u, f, kv);
  else    load_state_fb<false>(U0, F, KD, n, gb, d0, u, f, kv);
  float part[7];
  compute_partials7(act, u, f, kv, du, mbits, part);   // recompute du
#pragma unroll
  for (int e = 0; e < FEPT; ++e) u[e] = fmaf(ab, du[e], u[e]);
#pragma unroll
  for (int i = 0; i < 4; ++i)
    *(float4*)(g_UW + gb + 4*i) = make_float4(u[4*i], u[4*i+1], u[4*i+2], u[4*i+3]);
  if (last) {
    if (bf) store16<true >(OUT, gb, u);
    else    store16<false>(OUT, gb, u);
  }
}

extern "C" void kernel_launch(void* const* d_in, const int* in_sizes, int n_in,
                              void* d_out, int out_size, void* d_ws, size_t ws_size,
                              hipStream_t stream) {
  const void* F   = d_in[0];               // external_forces [B, DOF]
  const void* U0  = d_in[1];               // u0              [B, DOF]
  const void* KD  = d_in[2];               // k_diag          [DOF]
  const int*  FIX = (const int*)d_in[3];   // fixed_dofs      [NFIX] int32
  void* OUT = d_out;

  void* args[] = {(void*)&F, (void*)&U0, (void*)&KD, (void*)&FIX, (void*)&OUT};
  hipError_t e = hipLaunchCooperativeKernel((void*)k_coop, dim3(CGRID), dim3(CTPB),
                                            args, 0, stream);
  if (e != hipSuccess) {
    (void)hipGetLastError();               // clear sticky error, take fallback
    for (int n = 0; n < NEWTON; ++n) {
      k_part_fb<<<FGRID, FTPB, 0, stream>>>(F, U0, KD, FIX, n);
      k_upd_fb<<<FGRID, FTPB, 0, stream>>>(F, U0, KD, FIX, d_out, n,
                                           (n == NEWTON - 1) ? 1 : 0);
    }
  }
}